// Round 9
// baseline (331.166 us; speedup 1.0000x reference)
//
#include <hip/hip_runtime.h>
#include <stdint.h>

// ---------------- problem constants ----------------
#define GD 32
#define GH 512
#define GW 512
#define GDHW (GD * GH * GW)    // 8388608
#define KOFF 27
#define CAP 4096               // per-offset pair capacity (mean ~2685, sigma ~51)
#define CNTS 32                // counter stride in ints (128 B: one line each)
#define NW2 (KOFF * 128 * 128)

typedef __attribute__((ext_vector_type(8))) short short8;
typedef __attribute__((ext_vector_type(4))) float f32x4;

__device__ __forceinline__ unsigned short f32_to_bf16(float x) {
    unsigned int u = __float_as_uint(x);
    unsigned int r = (u + 0x7FFFu + ((u >> 16) & 1u)) >> 16;
    return (unsigned short)r;
}

// ---------------- setup: scatter(+bitmask) + w2prep --------------------------
__global__ __launch_bounds__(256) void setup_kernel(
    const int* __restrict__ coors, int* __restrict__ grid,
    unsigned int* __restrict__ bitgrid,
    const float* __restrict__ w2, unsigned short* __restrict__ w2t,
    int n, int nbsc) {
    const int bid = blockIdx.x, t = threadIdx.x;
    if (bid < nbsc) {
        int i = bid * 256 + t;
        if (i < n) {
            int z = coors[i * 4 + 1];
            int y = coors[i * 4 + 2];
            int x = coors[i * 4 + 3];
            int cell = (z * GH + y) * GW + x;
            grid[cell] = i;
            atomicOr(&bitgrid[cell >> 5], 1u << (cell & 31));
        }
    } else {
        int g = (bid - nbsc) * 256 + t;
        if (g < NW2) {
            int k = g >> 14;           // offset
            int c = (g >> 7) & 127;    // cout
            int q = g & 127;           // cin
            w2t[g] = f32_to_bf16(w2[(k * 128 + q) * 128 + c]);
        }
    }
}

// ---------------- nbr1: hoisted word-loads + FUSED last-block scan ----------
// Probe phase identical to R8 (18 branch-free word loads, immediate compact).
// The last-arriving block runs the 26 exclusive prefix-scans via wave-level
// __shfl_up (no barriers) -> bbase + cnts. Eliminates the scan dispatch.
__global__ __launch_bounds__(256) void nbr1_kernel(
    const int* __restrict__ coors, const int* __restrict__ grid,
    const unsigned int* __restrict__ bitgrid,
    int* __restrict__ vcnt, int* __restrict__ nbrc,
    unsigned long long* __restrict__ wmask, int* __restrict__ bcnt,
    int* __restrict__ bbase, int* __restrict__ cnts, int* __restrict__ done,
    int n, int nb) {
    __shared__ int wcnt[4][26];
    __shared__ int sdone;

    const int bid = blockIdx.x;
    const int i = bid * 256 + threadIdx.x;
    const int t = threadIdx.x, wave = t >> 6, lane = t & 63;
    const bool live = (i < n);

    int z = 0, y = 0, x = 0;
    if (live) {
        z = coors[i * 4 + 1];
        y = coors[i * 4 + 2];
        x = coors[i * 4 + 3];
    }

    // ---- 9 rows x 2 unconditional word loads (all independent) ----
    int c0r[9];
    bool rowok[9];
    unsigned int wlo[9], whi[9];
#pragma unroll
    for (int r = 0; r < 9; ++r) {
        int dz = r / 3 - 1, dy = r % 3 - 1;
        int nz = z + dz, ny = y + dy;
        int cz = min(max(nz, 0), GD - 1);
        int cy = min(max(ny, 0), GH - 1);
        int c0 = (cz * GH + cy) * GW + x;
        c0r[r] = c0;
        rowok[r] = live && nz >= 0 && nz < GD && ny >= 0 && ny < GH;
        wlo[r] = bitgrid[(c0 - 1) >> 5];   // legal: ws memory before bitgrid
        whi[r] = bitgrid[(c0 + 1) >> 5];   // legal: ws memory after bitgrid
    }

    // ---- extract 26 bits, compact hits immediately ----
    unsigned int mask26 = 0;
    int c = 0;
#pragma unroll
    for (int k = 0; k < 27; ++k) {
        if (k == 13) continue;
        int r = k / 3, dx = k % 3 - 1;
        int nx = x + dx;
        int cell = c0r[r] + dx;
        bool ok = rowok[r] && nx >= 0 && nx < GW;
        unsigned int w;
        if (dx < 0) w = wlo[r];
        else if (dx > 0) w = whi[r];
        else w = ((cell & 31) == 0) ? whi[r] : wlo[r];
        bool occ = ok && ((w >> (cell & 31)) & 1u);
        if (occ) {
            int jj = grid[cell];               // rare: ~0.47 hits/voxel
            nbrc[i * 27 + c] = (k << 20) | jj;
            ++c;
            mask26 |= 1u << (k - (k > 13));
        }
    }
    if (live) vcnt[i] = c;

    // ---- per-wave ballots + per-block counts (plain stores only) ----
#pragma unroll
    for (int kk = 0; kk < 26; ++kk) {
        unsigned long long m = __ballot((mask26 >> kk) & 1u);
        if (lane == 0) {
            wmask[((size_t)bid * 4 + wave) * 26 + kk] = m;
            wcnt[wave][kk] = __popcll(m);
        }
    }
    __syncthreads();
    if (t < 26)
        bcnt[t * nb + bid] = wcnt[0][t] + wcnt[1][t] + wcnt[2][t] + wcnt[3][t];

    // ---- fused scan: last-arriving block does all 26 prefix sums ----
    __syncthreads();
    __threadfence();
    if (t == 0) sdone = atomicAdd(done, 1);
    __syncthreads();
    if (sdone != nb - 1) return;
    __threadfence();                         // acquire: all bcnt visible

    const int nchunk = (nb + 63) / 64;
    for (int k = wave; k < 26; k += 4) {     // wave-parallel over offsets
        int running = 0;
        for (int ch = 0; ch < nchunk; ++ch) {
            int idx = ch * 64 + lane;
            int v = (idx < nb) ? bcnt[k * nb + idx] : 0;
            int orig = v;
#pragma unroll
            for (int off = 1; off < 64; off <<= 1) {   // inclusive wave scan
                int u = __shfl_up(v, off);
                if (lane >= off) v += u;
            }
            if (idx < nb) bbase[k * nb + idx] = running + v - orig;
            running += __shfl(v, 63);
        }
        if (lane == 0) cnts[k * CNTS] = running;
    }
}

// ---------------- nbr2 + conv1 merged (both depend only on nbr1) ------------
__global__ __launch_bounds__(256) void nbr2_conv1_kernel(
    const int* __restrict__ vcnt, const int* __restrict__ nbrc,
    const unsigned long long* __restrict__ wmask,
    const int* __restrict__ bbase,
    int* __restrict__ pairs, int* __restrict__ npos,
    const float* __restrict__ feat, const float* __restrict__ w1,
    unsigned short* __restrict__ hout, int n, int nb) {
    const int t = threadIdx.x;
    const int wave = t >> 6, lane = t & 63;

    if (blockIdx.x < (unsigned)nb) {
        // ---- nbr2 role: emit pairs/npos at exact ranks (no atomics) ----
        __shared__ unsigned long long lmsk[4][26];
        __shared__ int woff[4][26];
        __shared__ int bb[26];

        const int bid = blockIdx.x;
        if (t < 26) {
            unsigned long long m0 = wmask[((size_t)bid * 4 + 0) * 26 + t];
            unsigned long long m1 = wmask[((size_t)bid * 4 + 1) * 26 + t];
            unsigned long long m2 = wmask[((size_t)bid * 4 + 2) * 26 + t];
            unsigned long long m3 = wmask[((size_t)bid * 4 + 3) * 26 + t];
            lmsk[0][t] = m0; lmsk[1][t] = m1; lmsk[2][t] = m2; lmsk[3][t] = m3;
            int p0 = __popcll(m0), p1 = __popcll(m1), p2 = __popcll(m2);
            woff[0][t] = 0; woff[1][t] = p0; woff[2][t] = p0 + p1;
            woff[3][t] = p0 + p1 + p2;
            bb[t] = bbase[t * nb + bid];
        }
        __syncthreads();

        const int i = bid * 256 + t;
        if (i >= n) return;
        const unsigned long long lmask = (1ull << lane) - 1;
        const int cnt = vcnt[i];
        for (int s = 0; s < cnt; ++s) {
            int e = nbrc[i * 27 + s];
            int k = e >> 20, j = e & 0xFFFFF;
            int kk = k - (k > 13);
            int pos = bb[kk] + woff[wave][kk] +
                      __popcll(lmsk[wave][kk] & lmask);
            if (pos < CAP) {
                pairs[kk * CAP + pos] = j;
                npos[i * 27 + s] = kk * CAP + pos;
            } else {
                npos[i * 27 + s] = -1;
            }
        }
        return;
    }

    // ---- conv1 role: Cin=3 -> 128, compacted gather, bf16 out ----
    const int i = (blockIdx.x - nb) * 4 + wave;
    if (i >= n) return;
    const int c2 = lane * 2;

    const int cnt = vcnt[i];
    float f0 = feat[i * 3 + 0];
    float f1 = feat[i * 3 + 1];
    float f2 = feat[i * 3 + 2];

    const float* wc = w1 + 13 * 384 + c2;
    float2 w0 = *(const float2*)(wc);
    float2 wv1 = *(const float2*)(wc + 128);
    float2 w2_ = *(const float2*)(wc + 256);
    float a0 = f0 * w0.x + f1 * wv1.x + f2 * w2_.x;
    float a1 = f0 * w0.y + f1 * wv1.y + f2 * w2_.y;

    for (int s = 0; s < cnt; ++s) {          // wave-uniform trip count
        int e = nbrc[i * 27 + s];
        int k = e >> 20, jj = e & 0xFFFFF;
        float g0 = feat[jj * 3 + 0];
        float g1 = feat[jj * 3 + 1];
        float g2 = feat[jj * 3 + 2];
        const float* wk = w1 + k * 384 + c2;
        float2 u0 = *(const float2*)(wk);
        float2 u1 = *(const float2*)(wk + 128);
        float2 u2 = *(const float2*)(wk + 256);
        a0 += g0 * u0.x + g1 * u1.x + g2 * u2.x;
        a1 += g0 * u0.y + g1 * u1.y + g2 * u2.y;
    }

    unsigned int packed = (unsigned int)f32_to_bf16(a0) |
                          ((unsigned int)f32_to_bf16(a1) << 16);
    *(unsigned int*)(hout + (size_t)i * 128 + c2) = packed;
}

// ---------------- conv2b: bucketed gather-GEMM -> bf16 corr rows ------------
__global__ __launch_bounds__(256, 2) void conv2b_kernel(
    const unsigned short* __restrict__ h,
    const unsigned short* __restrict__ w2t,
    const int* __restrict__ pairs, const int* __restrict__ cnts,
    unsigned short* __restrict__ corr) {
    const int kb = blockIdx.x >> 5;
    const int tile = blockIdx.x & 31;
    const int cnt = min(cnts[kb * CNTS], CAP);
    const int base = tile * 128;
    if (base >= cnt) return;              // uniform early-exit
    const int m = min(128, cnt - base);
    const int k = kb + (kb >= 13);
    const int* pk = pairs + kb * CAP + base;

    const int t = threadIdx.x;
    const int wave = t >> 6, lane = t & 63;
    const int lane16 = lane & 15, quad = lane >> 4;
    const int wm = wave >> 1, wn = wave & 1;

    short8 a[4][4];
#pragma unroll
    for (int ms = 0; ms < 4; ++ms) {
        int r = wm * 64 + ms * 16 + lane16;
        bool v = (r < m);
        int j = v ? pk[r] : 0;
        const unsigned short* hp = h + (size_t)j * 128 + quad * 8;
#pragma unroll
        for (int ks = 0; ks < 4; ++ks)
            a[ms][ks] = v ? *(const short8*)(hp + ks * 32)
                          : (short8){0, 0, 0, 0, 0, 0, 0, 0};
    }

    short8 b[4][4];
    const unsigned short* wbase = w2t + (size_t)k * 16384 + quad * 8;
#pragma unroll
    for (int ns = 0; ns < 4; ++ns) {
        int c = wn * 64 + ns * 16 + lane16;
        const unsigned short* wp = wbase + c * 128;
#pragma unroll
        for (int ks = 0; ks < 4; ++ks)
            b[ns][ks] = *(const short8*)(wp + ks * 32);
    }

    f32x4 acc[4][4];
#pragma unroll
    for (int p = 0; p < 4; ++p)
#pragma unroll
        for (int q = 0; q < 4; ++q) acc[p][q] = (f32x4){0.f, 0.f, 0.f, 0.f};

#pragma unroll
    for (int ks = 0; ks < 4; ++ks)
#pragma unroll
        for (int ns = 0; ns < 4; ++ns)
#pragma unroll
            for (int ms = 0; ms < 4; ++ms)
                acc[ms][ns] = __builtin_amdgcn_mfma_f32_16x16x32_bf16(
                    a[ms][ks], b[ns][ks], acc[ms][ns], 0, 0, 0);

#pragma unroll
    for (int ms = 0; ms < 4; ++ms) {
#pragma unroll
        for (int r = 0; r < 4; ++r) {
            int row = wm * 64 + ms * 16 + quad * 4 + r;
            if (row < m) {
                unsigned short* cr =
                    corr + (size_t)(kb * CAP + base + row) * 128;
#pragma unroll
                for (int ns = 0; ns < 4; ++ns) {
                    int col = wn * 64 + ns * 16 + lane16;
                    cr[col] = f32_to_bf16(acc[ms][ns][r]);
                }
            }
        }
    }
}

// ---------------- conv2a + fixup fused: center GEMM, corr-add in epilogue ---
// out written exactly ONCE (saves the 114 MB fixup RMW + one dispatch).
__global__ __launch_bounds__(256, 2) void conv2a_fix_kernel(
    const unsigned short* __restrict__ h,
    const unsigned short* __restrict__ w2t,
    const int* __restrict__ vcnt, const int* __restrict__ npos,
    const unsigned short* __restrict__ corr,
    float* __restrict__ out, int n) {
    const int t = threadIdx.x;
    const int wave = t >> 6, lane = t & 63;
    const int lane16 = lane & 15, quad = lane >> 4;
    const int wm = wave >> 1, wn = wave & 1;
    const int row0 = blockIdx.x * 128;

    short8 a[4][4];
#pragma unroll
    for (int ms = 0; ms < 4; ++ms) {
        int r = row0 + wm * 64 + ms * 16 + lane16;
        r = min(r, n - 1);                        // clamp: dup rows, never OOB
        const unsigned short* hp = h + (size_t)r * 128 + quad * 8;
#pragma unroll
        for (int ks = 0; ks < 4; ++ks)
            a[ms][ks] = *(const short8*)(hp + ks * 32);
    }

    short8 b[4][4];
    const unsigned short* wbase = w2t + 13 * 16384 + quad * 8;
#pragma unroll
    for (int ns = 0; ns < 4; ++ns) {
        int c = wn * 64 + ns * 16 + lane16;
        const unsigned short* wp = wbase + c * 128;
#pragma unroll
        for (int ks = 0; ks < 4; ++ks)
            b[ns][ks] = *(const short8*)(wp + ks * 32);
    }

    f32x4 acc[4][4];
#pragma unroll
    for (int p = 0; p < 4; ++p)
#pragma unroll
        for (int q = 0; q < 4; ++q) acc[p][q] = (f32x4){0.f, 0.f, 0.f, 0.f};

#pragma unroll
    for (int ks = 0; ks < 4; ++ks)
#pragma unroll
        for (int ns = 0; ns < 4; ++ns)
#pragma unroll
            for (int ms = 0; ms < 4; ++ms)
                acc[ms][ns] = __builtin_amdgcn_mfma_f32_16x16x32_bf16(
                    a[ms][ks], b[ns][ks], acc[ms][ns], 0, 0, 0);

    // ---- epilogue: add correction rows (avg ~0.47/row), then single store --
#pragma unroll
    for (int ms = 0; ms < 4; ++ms) {
#pragma unroll
        for (int r = 0; r < 4; ++r) {
            int i = row0 + wm * 64 + ms * 16 + quad * 4 + r;
            if (i < n) {
                const int cnt = vcnt[i];                 // quad-uniform
                const int* np = npos + i * 27;
                for (int s = 0; s < cnt; ++s) {
                    int p = np[s];
                    if (p >= 0) {
                        const unsigned short* cr =
                            corr + (size_t)p * 128 + wn * 64 + lane16;
#pragma unroll
                        for (int ns = 0; ns < 4; ++ns) {
                            unsigned int uv = cr[ns * 16];
                            acc[ms][ns][r] += __uint_as_float(uv << 16);
                        }
                    }
                }
#pragma unroll
                for (int ns = 0; ns < 4; ++ns) {
                    int col = wn * 64 + ns * 16 + lane16;
                    out[(size_t)i * 128 + col] = acc[ms][ns][r];
                }
            }
        }
    }
}

// ---------------- launch ----------------
extern "C" void kernel_launch(void* const* d_in, const int* in_sizes, int n_in,
                              void* d_out, int out_size, void* d_ws,
                              size_t ws_size, hipStream_t stream) {
    const float* feat = (const float*)d_in[0];   // [n][3] f32
    const int* coors = (const int*)d_in[1];      // [n][4] i32
    const float* w1 = (const float*)d_in[2];     // [27][3][128] f32
    const float* w2 = (const float*)d_in[3];     // [27][128][128] f32
    float* out = (float*)d_out;                  // [n][128] f32

    const int n = in_sizes[0] / 3;
    const int nb = (n + 255) / 256;              // voxel blocks

    uint8_t* ws = (uint8_t*)d_ws;
    size_t off = 0;
    int* grid = (int*)(ws + off); off += (size_t)GDHW * 4;            // 32 MB
    unsigned int* bitgrid = (unsigned int*)(ws + off);
    off += (size_t)(GDHW / 8);                                        // 1 MB
    int* done = (int*)(ws + off); off += 256;    // covered by bitgrid memset
    int* vcnt = (int*)(ws + off); off += (size_t)n * 4;               // 0.6 MB
    int* nbrc = (int*)(ws + off); off += (size_t)n * 27 * 4;          // 16.2 MB
    int* npos = (int*)(ws + off); off += (size_t)n * 27 * 4;          // 16.2 MB
    off = (off + 255) & ~(size_t)255;
    unsigned long long* wmask = (unsigned long long*)(ws + off);
    off += (size_t)nb * 4 * 26 * 8;                                   // 0.49 MB
    int* bcnt = (int*)(ws + off); off += (size_t)26 * nb * 4;         // 61 KB
    int* bbase = (int*)(ws + off); off += (size_t)26 * nb * 4;        // 61 KB
    off = (off + 255) & ~(size_t)255;
    unsigned short* hbuf = (unsigned short*)(ws + off);
    off += (size_t)n * 128 * 2;                                       // 38.4 MB
    off = (off + 255) & ~(size_t)255;
    unsigned short* w2t = (unsigned short*)(ws + off);
    off += (size_t)KOFF * 128 * 128 * 2;                              // 0.85 MB
    off = (off + 255) & ~(size_t)255;
    int* pairs = (int*)(ws + off);
    off += (size_t)26 * CAP * 4;                                      // 0.43 MB
    off = (off + 255) & ~(size_t)255;
    int* cnts = (int*)(ws + off); off += 26 * CNTS * 4;               // 3.3 KB
    off = (off + 255) & ~(size_t)255;
    unsigned short* corr = (unsigned short*)(ws + off);
    off += (size_t)26 * CAP * 128 * 2;                                // 27.3 MB

    // one memset covers bitgrid (1 MB) + the done counter right after it
    hipMemsetAsync(bitgrid, 0x00, (size_t)(GDHW / 8) + 256, stream);

    const int nbw2 = (NW2 + 255) / 256;
    setup_kernel<<<nb + nbw2, 256, 0, stream>>>(coors, grid, bitgrid, w2, w2t,
                                                n, nb);
    nbr1_kernel<<<nb, 256, 0, stream>>>(coors, grid, bitgrid, vcnt, nbrc,
                                        wmask, bcnt, bbase, cnts, done, n, nb);
    nbr2_conv1_kernel<<<nb + (n + 3) / 4, 256, 0, stream>>>(
        vcnt, nbrc, wmask, bbase, pairs, npos, feat, w1, hbuf, n, nb);
    conv2b_kernel<<<26 * 32, 256, 0, stream>>>(hbuf, w2t, pairs, cnts, corr);
    conv2a_fix_kernel<<<(n + 127) / 128, 256, 0, stream>>>(
        hbuf, w2t, vcnt, npos, corr, out, n);
}

// Round 10
// 243.494 us; speedup vs baseline: 1.3601x; 1.3601x over previous
//
#include <hip/hip_runtime.h>
#include <stdint.h>

// ---------------- problem constants ----------------
#define GD 32
#define GH 512
#define GW 512
#define GDHW (GD * GH * GW)    // 8388608
#define KOFF 27
#define CAP 4096               // per-offset pair capacity (mean ~2685, sigma ~51)
#define CNTS 32                // counter stride in ints (128 B: one line each)
#define NW2 (KOFF * 128 * 128)

typedef __attribute__((ext_vector_type(8))) short short8;
typedef __attribute__((ext_vector_type(4))) float f32x4;

__device__ __forceinline__ unsigned short f32_to_bf16(float x) {
    unsigned int u = __float_as_uint(x);
    unsigned int r = (u + 0x7FFFu + ((u >> 16) & 1u)) >> 16;
    return (unsigned short)r;
}

// ---------------- setup: scatter(+bitmask) + w2prep --------------------------
__global__ __launch_bounds__(256) void setup_kernel(
    const int* __restrict__ coors, int* __restrict__ grid,
    unsigned int* __restrict__ bitgrid,
    const float* __restrict__ w2, unsigned short* __restrict__ w2t,
    int n, int nbsc) {
    const int bid = blockIdx.x, t = threadIdx.x;
    if (bid < nbsc) {
        int i = bid * 256 + t;
        if (i < n) {
            int z = coors[i * 4 + 1];
            int y = coors[i * 4 + 2];
            int x = coors[i * 4 + 3];
            int cell = (z * GH + y) * GW + x;
            grid[cell] = i;
            atomicOr(&bitgrid[cell >> 5], 1u << (cell & 31));
        }
    } else {
        int g = (bid - nbsc) * 256 + t;
        if (g < NW2) {
            int k = g >> 14;           // offset
            int c = (g >> 7) & 127;    // cout
            int q = g & 127;           // cin
            w2t[g] = f32_to_bf16(w2[(k * 128 + q) * 128 + c]);
        }
    }
}

// ---------------- nbr1: 18 hoisted word-loads, immediate compaction ---------
// NO device-scope fences here (R9 lesson: threadfence in a wide kernel
// serializes on multi-XCD; the kernel boundary is the cheap global fence).
__global__ __launch_bounds__(256) void nbr1_kernel(
    const int* __restrict__ coors, const int* __restrict__ grid,
    const unsigned int* __restrict__ bitgrid,
    int* __restrict__ vcnt, int* __restrict__ nbrc,
    unsigned long long* __restrict__ wmask, int* __restrict__ bcnt,
    int n, int nb) {
    __shared__ int wcnt[4][26];

    const int bid = blockIdx.x;
    const int i = bid * 256 + threadIdx.x;
    const int t = threadIdx.x, wave = t >> 6, lane = t & 63;
    const bool live = (i < n);

    int z = 0, y = 0, x = 0;
    if (live) {
        z = coors[i * 4 + 1];
        y = coors[i * 4 + 2];
        x = coors[i * 4 + 3];
    }

    // ---- 9 rows x 2 unconditional word loads (all independent) ----
    int c0r[9];
    bool rowok[9];
    unsigned int wlo[9], whi[9];
#pragma unroll
    for (int r = 0; r < 9; ++r) {
        int dz = r / 3 - 1, dy = r % 3 - 1;
        int nz = z + dz, ny = y + dy;
        int cz = min(max(nz, 0), GD - 1);
        int cy = min(max(ny, 0), GH - 1);
        int c0 = (cz * GH + cy) * GW + x;
        c0r[r] = c0;
        rowok[r] = live && nz >= 0 && nz < GD && ny >= 0 && ny < GH;
        wlo[r] = bitgrid[(c0 - 1) >> 5];   // legal: ws memory before bitgrid
        whi[r] = bitgrid[(c0 + 1) >> 5];   // legal: ws memory after bitgrid
    }

    // ---- extract 26 bits, compact hits immediately ----
    unsigned int mask26 = 0;
    int c = 0;
#pragma unroll
    for (int k = 0; k < 27; ++k) {
        if (k == 13) continue;
        int r = k / 3, dx = k % 3 - 1;
        int nx = x + dx;
        int cell = c0r[r] + dx;
        bool ok = rowok[r] && nx >= 0 && nx < GW;
        unsigned int w;
        if (dx < 0) w = wlo[r];
        else if (dx > 0) w = whi[r];
        else w = ((cell & 31) == 0) ? whi[r] : wlo[r];
        bool occ = ok && ((w >> (cell & 31)) & 1u);
        if (occ) {
            int jj = grid[cell];               // rare: ~0.47 hits/voxel
            nbrc[i * 27 + c] = (k << 20) | jj;
            ++c;
            mask26 |= 1u << (k - (k > 13));
        }
    }
    if (live) vcnt[i] = c;

    // ---- per-wave ballots + per-block counts (plain stores only) ----
#pragma unroll
    for (int kk = 0; kk < 26; ++kk) {
        unsigned long long m = __ballot((mask26 >> kk) & 1u);
        if (lane == 0) {
            wmask[((size_t)bid * 4 + wave) * 26 + kk] = m;
            wcnt[wave][kk] = __popcll(m);
        }
    }
    __syncthreads();
    if (t < 26)
        bcnt[t * nb + bid] = wcnt[0][t] + wcnt[1][t] + wcnt[2][t] + wcnt[3][t];
}

// ---------------- scan: 26 blocks, exclusive prefix over nb block-counts ----
// Standalone tiny dispatch (proven free in R6/R7) -- the kernel boundary
// provides the cross-XCD visibility that R9's threadfence paid 90 us for.
__global__ __launch_bounds__(256) void scan_kernel(
    const int* __restrict__ bcnt, int* __restrict__ bbase,
    int* __restrict__ cnts, int nb) {
    const int k = blockIdx.x;   // 0..25
    const int t = threadIdx.x;
    __shared__ int s[256];
    int run = 0;
    for (int base = 0; base < nb; base += 256) {
        int idx = base + t;
        int v = (idx < nb) ? bcnt[k * nb + idx] : 0;
        s[t] = v;
        __syncthreads();
        for (int off = 1; off < 256; off <<= 1) {
            int u = (t >= off) ? s[t - off] : 0;
            __syncthreads();
            s[t] += u;
            __syncthreads();
        }
        int incl = s[t];
        int total = s[255];
        if (idx < nb) bbase[k * nb + idx] = run + incl - v;
        run += total;
        __syncthreads();
    }
    if (t == 0) cnts[k * CNTS] = run;
}

// ---------------- nbr2 + conv1 merged (both depend only on nbr1+scan) -------
__global__ __launch_bounds__(256) void nbr2_conv1_kernel(
    const int* __restrict__ vcnt, const int* __restrict__ nbrc,
    const unsigned long long* __restrict__ wmask,
    const int* __restrict__ bbase,
    int* __restrict__ pairs, int* __restrict__ npos,
    const float* __restrict__ feat, const float* __restrict__ w1,
    unsigned short* __restrict__ hout, int n, int nb) {
    const int t = threadIdx.x;
    const int wave = t >> 6, lane = t & 63;

    if (blockIdx.x < (unsigned)nb) {
        // ---- nbr2 role: emit pairs/npos at exact ranks (no atomics) ----
        __shared__ unsigned long long lmsk[4][26];
        __shared__ int woff[4][26];
        __shared__ int bb[26];

        const int bid = blockIdx.x;
        if (t < 26) {
            unsigned long long m0 = wmask[((size_t)bid * 4 + 0) * 26 + t];
            unsigned long long m1 = wmask[((size_t)bid * 4 + 1) * 26 + t];
            unsigned long long m2 = wmask[((size_t)bid * 4 + 2) * 26 + t];
            unsigned long long m3 = wmask[((size_t)bid * 4 + 3) * 26 + t];
            lmsk[0][t] = m0; lmsk[1][t] = m1; lmsk[2][t] = m2; lmsk[3][t] = m3;
            int p0 = __popcll(m0), p1 = __popcll(m1), p2 = __popcll(m2);
            woff[0][t] = 0; woff[1][t] = p0; woff[2][t] = p0 + p1;
            woff[3][t] = p0 + p1 + p2;
            bb[t] = bbase[t * nb + bid];
        }
        __syncthreads();

        const int i = bid * 256 + t;
        if (i >= n) return;
        const unsigned long long lmask = (1ull << lane) - 1;
        const int cnt = vcnt[i];
        for (int s = 0; s < cnt; ++s) {
            int e = nbrc[i * 27 + s];
            int k = e >> 20, j = e & 0xFFFFF;
            int kk = k - (k > 13);
            int pos = bb[kk] + woff[wave][kk] +
                      __popcll(lmsk[wave][kk] & lmask);
            if (pos < CAP) {
                pairs[kk * CAP + pos] = j;
                npos[i * 27 + s] = kk * CAP + pos;
            } else {
                npos[i * 27 + s] = -1;
            }
        }
        return;
    }

    // ---- conv1 role: Cin=3 -> 128, compacted gather, bf16 out ----
    const int i = (blockIdx.x - nb) * 4 + wave;
    if (i >= n) return;
    const int c2 = lane * 2;

    const int cnt = vcnt[i];
    float f0 = feat[i * 3 + 0];
    float f1 = feat[i * 3 + 1];
    float f2 = feat[i * 3 + 2];

    const float* wc = w1 + 13 * 384 + c2;
    float2 w0 = *(const float2*)(wc);
    float2 wv1 = *(const float2*)(wc + 128);
    float2 w2_ = *(const float2*)(wc + 256);
    float a0 = f0 * w0.x + f1 * wv1.x + f2 * w2_.x;
    float a1 = f0 * w0.y + f1 * wv1.y + f2 * w2_.y;

    for (int s = 0; s < cnt; ++s) {          // wave-uniform trip count
        int e = nbrc[i * 27 + s];
        int k = e >> 20, jj = e & 0xFFFFF;
        float g0 = feat[jj * 3 + 0];
        float g1 = feat[jj * 3 + 1];
        float g2 = feat[jj * 3 + 2];
        const float* wk = w1 + k * 384 + c2;
        float2 u0 = *(const float2*)(wk);
        float2 u1 = *(const float2*)(wk + 128);
        float2 u2 = *(const float2*)(wk + 256);
        a0 += g0 * u0.x + g1 * u1.x + g2 * u2.x;
        a1 += g0 * u0.y + g1 * u1.y + g2 * u2.y;
    }

    unsigned int packed = (unsigned int)f32_to_bf16(a0) |
                          ((unsigned int)f32_to_bf16(a1) << 16);
    *(unsigned int*)(hout + (size_t)i * 128 + c2) = packed;
}

// ---------------- conv2b: bucketed gather-GEMM -> bf16 corr rows ------------
__global__ __launch_bounds__(256, 2) void conv2b_kernel(
    const unsigned short* __restrict__ h,
    const unsigned short* __restrict__ w2t,
    const int* __restrict__ pairs, const int* __restrict__ cnts,
    unsigned short* __restrict__ corr) {
    const int kb = blockIdx.x >> 5;
    const int tile = blockIdx.x & 31;
    const int cnt = min(cnts[kb * CNTS], CAP);
    const int base = tile * 128;
    if (base >= cnt) return;              // uniform early-exit
    const int m = min(128, cnt - base);
    const int k = kb + (kb >= 13);
    const int* pk = pairs + kb * CAP + base;

    const int t = threadIdx.x;
    const int wave = t >> 6, lane = t & 63;
    const int lane16 = lane & 15, quad = lane >> 4;
    const int wm = wave >> 1, wn = wave & 1;

    short8 a[4][4];
#pragma unroll
    for (int ms = 0; ms < 4; ++ms) {
        int r = wm * 64 + ms * 16 + lane16;
        bool v = (r < m);
        int j = v ? pk[r] : 0;
        const unsigned short* hp = h + (size_t)j * 128 + quad * 8;
#pragma unroll
        for (int ks = 0; ks < 4; ++ks)
            a[ms][ks] = v ? *(const short8*)(hp + ks * 32)
                          : (short8){0, 0, 0, 0, 0, 0, 0, 0};
    }

    short8 b[4][4];
    const unsigned short* wbase = w2t + (size_t)k * 16384 + quad * 8;
#pragma unroll
    for (int ns = 0; ns < 4; ++ns) {
        int c = wn * 64 + ns * 16 + lane16;
        const unsigned short* wp = wbase + c * 128;
#pragma unroll
        for (int ks = 0; ks < 4; ++ks)
            b[ns][ks] = *(const short8*)(wp + ks * 32);
    }

    f32x4 acc[4][4];
#pragma unroll
    for (int p = 0; p < 4; ++p)
#pragma unroll
        for (int q = 0; q < 4; ++q) acc[p][q] = (f32x4){0.f, 0.f, 0.f, 0.f};

#pragma unroll
    for (int ks = 0; ks < 4; ++ks)
#pragma unroll
        for (int ns = 0; ns < 4; ++ns)
#pragma unroll
            for (int ms = 0; ms < 4; ++ms)
                acc[ms][ns] = __builtin_amdgcn_mfma_f32_16x16x32_bf16(
                    a[ms][ks], b[ns][ks], acc[ms][ns], 0, 0, 0);

#pragma unroll
    for (int ms = 0; ms < 4; ++ms) {
#pragma unroll
        for (int r = 0; r < 4; ++r) {
            int row = wm * 64 + ms * 16 + quad * 4 + r;
            if (row < m) {
                unsigned short* cr =
                    corr + (size_t)(kb * CAP + base + row) * 128;
#pragma unroll
                for (int ns = 0; ns < 4; ++ns) {
                    int col = wn * 64 + ns * 16 + lane16;
                    cr[col] = f32_to_bf16(acc[ms][ns][r]);
                }
            }
        }
    }
}

// ---------------- conv2a + fixup fused: center GEMM, corr-add in epilogue ---
// out written exactly ONCE (saves the 114 MB fixup RMW + one dispatch).
__global__ __launch_bounds__(256, 2) void conv2a_fix_kernel(
    const unsigned short* __restrict__ h,
    const unsigned short* __restrict__ w2t,
    const int* __restrict__ vcnt, const int* __restrict__ npos,
    const unsigned short* __restrict__ corr,
    float* __restrict__ out, int n) {
    const int t = threadIdx.x;
    const int wave = t >> 6, lane = t & 63;
    const int lane16 = lane & 15, quad = lane >> 4;
    const int wm = wave >> 1, wn = wave & 1;
    const int row0 = blockIdx.x * 128;

    short8 a[4][4];
#pragma unroll
    for (int ms = 0; ms < 4; ++ms) {
        int r = row0 + wm * 64 + ms * 16 + lane16;
        r = min(r, n - 1);                        // clamp: dup rows, never OOB
        const unsigned short* hp = h + (size_t)r * 128 + quad * 8;
#pragma unroll
        for (int ks = 0; ks < 4; ++ks)
            a[ms][ks] = *(const short8*)(hp + ks * 32);
    }

    short8 b[4][4];
    const unsigned short* wbase = w2t + 13 * 16384 + quad * 8;
#pragma unroll
    for (int ns = 0; ns < 4; ++ns) {
        int c = wn * 64 + ns * 16 + lane16;
        const unsigned short* wp = wbase + c * 128;
#pragma unroll
        for (int ks = 0; ks < 4; ++ks)
            b[ns][ks] = *(const short8*)(wp + ks * 32);
    }

    f32x4 acc[4][4];
#pragma unroll
    for (int p = 0; p < 4; ++p)
#pragma unroll
        for (int q = 0; q < 4; ++q) acc[p][q] = (f32x4){0.f, 0.f, 0.f, 0.f};

#pragma unroll
    for (int ks = 0; ks < 4; ++ks)
#pragma unroll
        for (int ns = 0; ns < 4; ++ns)
#pragma unroll
            for (int ms = 0; ms < 4; ++ms)
                acc[ms][ns] = __builtin_amdgcn_mfma_f32_16x16x32_bf16(
                    a[ms][ks], b[ns][ks], acc[ms][ns], 0, 0, 0);

    // ---- epilogue: add correction rows (avg ~0.47/row), then single store --
#pragma unroll
    for (int ms = 0; ms < 4; ++ms) {
#pragma unroll
        for (int r = 0; r < 4; ++r) {
            int i = row0 + wm * 64 + ms * 16 + quad * 4 + r;
            if (i < n) {
                const int cnt = vcnt[i];                 // quad-uniform
                const int* np = npos + i * 27;
                for (int s = 0; s < cnt; ++s) {
                    int p = np[s];
                    if (p >= 0) {
                        const unsigned short* cr =
                            corr + (size_t)p * 128 + wn * 64 + lane16;
#pragma unroll
                        for (int ns = 0; ns < 4; ++ns) {
                            unsigned int uv = cr[ns * 16];
                            acc[ms][ns][r] += __uint_as_float(uv << 16);
                        }
                    }
                }
#pragma unroll
                for (int ns = 0; ns < 4; ++ns) {
                    int col = wn * 64 + ns * 16 + lane16;
                    out[(size_t)i * 128 + col] = acc[ms][ns][r];
                }
            }
        }
    }
}

// ---------------- launch ----------------
extern "C" void kernel_launch(void* const* d_in, const int* in_sizes, int n_in,
                              void* d_out, int out_size, void* d_ws,
                              size_t ws_size, hipStream_t stream) {
    const float* feat = (const float*)d_in[0];   // [n][3] f32
    const int* coors = (const int*)d_in[1];      // [n][4] i32
    const float* w1 = (const float*)d_in[2];     // [27][3][128] f32
    const float* w2 = (const float*)d_in[3];     // [27][128][128] f32
    float* out = (float*)d_out;                  // [n][128] f32

    const int n = in_sizes[0] / 3;
    const int nb = (n + 255) / 256;              // voxel blocks

    uint8_t* ws = (uint8_t*)d_ws;
    size_t off = 0;
    int* grid = (int*)(ws + off); off += (size_t)GDHW * 4;            // 32 MB
    unsigned int* bitgrid = (unsigned int*)(ws + off);
    off += (size_t)(GDHW / 8);                                        // 1 MB
    int* vcnt = (int*)(ws + off); off += (size_t)n * 4;               // 0.6 MB
    int* nbrc = (int*)(ws + off); off += (size_t)n * 27 * 4;          // 16.2 MB
    int* npos = (int*)(ws + off); off += (size_t)n * 27 * 4;          // 16.2 MB
    off = (off + 255) & ~(size_t)255;
    unsigned long long* wmask = (unsigned long long*)(ws + off);
    off += (size_t)nb * 4 * 26 * 8;                                   // 0.49 MB
    int* bcnt = (int*)(ws + off); off += (size_t)26 * nb * 4;         // 61 KB
    int* bbase = (int*)(ws + off); off += (size_t)26 * nb * 4;        // 61 KB
    off = (off + 255) & ~(size_t)255;
    unsigned short* hbuf = (unsigned short*)(ws + off);
    off += (size_t)n * 128 * 2;                                       // 38.4 MB
    off = (off + 255) & ~(size_t)255;
    unsigned short* w2t = (unsigned short*)(ws + off);
    off += (size_t)KOFF * 128 * 128 * 2;                              // 0.85 MB
    off = (off + 255) & ~(size_t)255;
    int* pairs = (int*)(ws + off);
    off += (size_t)26 * CAP * 4;                                      // 0.43 MB
    off = (off + 255) & ~(size_t)255;
    int* cnts = (int*)(ws + off); off += 26 * CNTS * 4;               // 3.3 KB
    off = (off + 255) & ~(size_t)255;
    unsigned short* corr = (unsigned short*)(ws + off);
    off += (size_t)26 * CAP * 128 * 2;                                // 27.3 MB

    // only the 1 MB bitmask needs clearing; int grid is read only where bit set
    hipMemsetAsync(bitgrid, 0x00, (size_t)(GDHW / 8), stream);

    const int nbw2 = (NW2 + 255) / 256;
    setup_kernel<<<nb + nbw2, 256, 0, stream>>>(coors, grid, bitgrid, w2, w2t,
                                                n, nb);
    nbr1_kernel<<<nb, 256, 0, stream>>>(coors, grid, bitgrid, vcnt, nbrc,
                                        wmask, bcnt, n, nb);
    scan_kernel<<<26, 256, 0, stream>>>(bcnt, bbase, cnts, nb);
    nbr2_conv1_kernel<<<nb + (n + 3) / 4, 256, 0, stream>>>(
        vcnt, nbrc, wmask, bbase, pairs, npos, feat, w1, hbuf, n, nb);
    conv2b_kernel<<<26 * 32, 256, 0, stream>>>(hbuf, w2t, pairs, cnts, corr);
    conv2a_fix_kernel<<<(n + 127) / 128, 256, 0, stream>>>(
        hbuf, w2t, vcnt, npos, corr, out, n);
}

// Round 11
// 228.676 us; speedup vs baseline: 1.4482x; 1.0648x over previous
//
#include <hip/hip_runtime.h>
#include <stdint.h>

// ---------------- problem constants ----------------
#define GD 32
#define GH 512
#define GW 512
#define GDHW (GD * GH * GW)    // 8388608
#define KOFF 27
#define CAP 4096               // per-offset pair capacity (mean ~2685, sigma ~51)
#define CNTS 32                // counter stride in ints (128 B: one line each)
#define NW2 (KOFF * 128 * 128)

typedef __attribute__((ext_vector_type(8))) short short8;
typedef __attribute__((ext_vector_type(4))) float f32x4;

__device__ __forceinline__ unsigned short f32_to_bf16(float x) {
    unsigned int u = __float_as_uint(x);
    unsigned int r = (u + 0x7FFFu + ((u >> 16) & 1u)) >> 16;
    return (unsigned short)r;
}

// ---------------- setup: scatter(+bitmask) + w2prep --------------------------
__global__ __launch_bounds__(256) void setup_kernel(
    const int* __restrict__ coors, int* __restrict__ grid,
    unsigned int* __restrict__ bitgrid,
    const float* __restrict__ w2, unsigned short* __restrict__ w2t,
    int n, int nbsc) {
    const int bid = blockIdx.x, t = threadIdx.x;
    if (bid < nbsc) {
        int i = bid * 256 + t;
        if (i < n) {
            int z = coors[i * 4 + 1];
            int y = coors[i * 4 + 2];
            int x = coors[i * 4 + 3];
            int cell = (z * GH + y) * GW + x;
            grid[cell] = i;
            atomicOr(&bitgrid[cell >> 5], 1u << (cell & 31));
        }
    } else {
        int g = (bid - nbsc) * 256 + t;
        if (g < NW2) {
            int k = g >> 14;           // offset
            int c = (g >> 7) & 127;    // cout
            int q = g & 127;           // cin
            w2t[g] = f32_to_bf16(w2[(k * 128 + q) * 128 + c]);
        }
    }
}

// ---------------- nbr1: 18 hoisted word-loads, immediate compaction ---------
// NO device-scope fences (R9 lesson: threadfence in a wide kernel serializes
// on multi-XCD; the kernel boundary is the cheap global fence).
__global__ __launch_bounds__(256) void nbr1_kernel(
    const int* __restrict__ coors, const int* __restrict__ grid,
    const unsigned int* __restrict__ bitgrid,
    int* __restrict__ vcnt, int* __restrict__ nbrc,
    unsigned long long* __restrict__ wmask, int* __restrict__ bcnt,
    int n, int nb) {
    __shared__ int wcnt[4][26];

    const int bid = blockIdx.x;
    const int i = bid * 256 + threadIdx.x;
    const int t = threadIdx.x, wave = t >> 6, lane = t & 63;
    const bool live = (i < n);

    int z = 0, y = 0, x = 0;
    if (live) {
        z = coors[i * 4 + 1];
        y = coors[i * 4 + 2];
        x = coors[i * 4 + 3];
    }

    // ---- 9 rows x 2 unconditional word loads (all independent) ----
    int c0r[9];
    bool rowok[9];
    unsigned int wlo[9], whi[9];
#pragma unroll
    for (int r = 0; r < 9; ++r) {
        int dz = r / 3 - 1, dy = r % 3 - 1;
        int nz = z + dz, ny = y + dy;
        int cz = min(max(nz, 0), GD - 1);
        int cy = min(max(ny, 0), GH - 1);
        int c0 = (cz * GH + cy) * GW + x;
        c0r[r] = c0;
        rowok[r] = live && nz >= 0 && nz < GD && ny >= 0 && ny < GH;
        wlo[r] = bitgrid[(c0 - 1) >> 5];   // legal: ws memory before bitgrid
        whi[r] = bitgrid[(c0 + 1) >> 5];   // legal: ws memory after bitgrid
    }

    // ---- extract 26 bits, compact hits immediately ----
    unsigned int mask26 = 0;
    int c = 0;
#pragma unroll
    for (int k = 0; k < 27; ++k) {
        if (k == 13) continue;
        int r = k / 3, dx = k % 3 - 1;
        int nx = x + dx;
        int cell = c0r[r] + dx;
        bool ok = rowok[r] && nx >= 0 && nx < GW;
        unsigned int w;
        if (dx < 0) w = wlo[r];
        else if (dx > 0) w = whi[r];
        else w = ((cell & 31) == 0) ? whi[r] : wlo[r];
        bool occ = ok && ((w >> (cell & 31)) & 1u);
        if (occ) {
            int jj = grid[cell];               // rare: ~0.47 hits/voxel
            nbrc[i * 27 + c] = (k << 20) | jj;
            ++c;
            mask26 |= 1u << (k - (k > 13));
        }
    }
    if (live) vcnt[i] = c;

    // ---- per-wave ballots + per-block counts (plain stores only) ----
#pragma unroll
    for (int kk = 0; kk < 26; ++kk) {
        unsigned long long m = __ballot((mask26 >> kk) & 1u);
        if (lane == 0) {
            wmask[((size_t)bid * 4 + wave) * 26 + kk] = m;
            wcnt[wave][kk] = __popcll(m);
        }
    }
    __syncthreads();
    if (t < 26)
        bcnt[t * nb + bid] = wcnt[0][t] + wcnt[1][t] + wcnt[2][t] + wcnt[3][t];
}

// ---------------- scan: 26 blocks, exclusive prefix over nb block-counts ----
__global__ __launch_bounds__(256) void scan_kernel(
    const int* __restrict__ bcnt, int* __restrict__ bbase,
    int* __restrict__ cnts, int nb) {
    const int k = blockIdx.x;   // 0..25
    const int t = threadIdx.x;
    __shared__ int s[256];
    int run = 0;
    for (int base = 0; base < nb; base += 256) {
        int idx = base + t;
        int v = (idx < nb) ? bcnt[k * nb + idx] : 0;
        s[t] = v;
        __syncthreads();
        for (int off = 1; off < 256; off <<= 1) {
            int u = (t >= off) ? s[t - off] : 0;
            __syncthreads();
            s[t] += u;
            __syncthreads();
        }
        int incl = s[t];
        int total = s[255];
        if (idx < nb) bbase[k * nb + idx] = run + incl - v;
        run += total;
        __syncthreads();
    }
    if (t == 0) cnts[k * CNTS] = run;
}

// ---------------- nbr2 + conv1 merged (both depend only on nbr1+scan) -------
__global__ __launch_bounds__(256) void nbr2_conv1_kernel(
    const int* __restrict__ vcnt, const int* __restrict__ nbrc,
    const unsigned long long* __restrict__ wmask,
    const int* __restrict__ bbase,
    int* __restrict__ pairs, int* __restrict__ npos,
    const float* __restrict__ feat, const float* __restrict__ w1,
    unsigned short* __restrict__ hout, int n, int nb) {
    const int t = threadIdx.x;
    const int wave = t >> 6, lane = t & 63;

    if (blockIdx.x < (unsigned)nb) {
        // ---- nbr2 role: emit pairs/npos at exact ranks (no atomics) ----
        __shared__ unsigned long long lmsk[4][26];
        __shared__ int woff[4][26];
        __shared__ int bb[26];

        const int bid = blockIdx.x;
        if (t < 26) {
            unsigned long long m0 = wmask[((size_t)bid * 4 + 0) * 26 + t];
            unsigned long long m1 = wmask[((size_t)bid * 4 + 1) * 26 + t];
            unsigned long long m2 = wmask[((size_t)bid * 4 + 2) * 26 + t];
            unsigned long long m3 = wmask[((size_t)bid * 4 + 3) * 26 + t];
            lmsk[0][t] = m0; lmsk[1][t] = m1; lmsk[2][t] = m2; lmsk[3][t] = m3;
            int p0 = __popcll(m0), p1 = __popcll(m1), p2 = __popcll(m2);
            woff[0][t] = 0; woff[1][t] = p0; woff[2][t] = p0 + p1;
            woff[3][t] = p0 + p1 + p2;
            bb[t] = bbase[t * nb + bid];
        }
        __syncthreads();

        const int i = bid * 256 + t;
        if (i >= n) return;
        const unsigned long long lmask = (1ull << lane) - 1;
        const int cnt = vcnt[i];
        for (int s = 0; s < cnt; ++s) {
            int e = nbrc[i * 27 + s];
            int k = e >> 20, j = e & 0xFFFFF;
            int kk = k - (k > 13);
            int pos = bb[kk] + woff[wave][kk] +
                      __popcll(lmsk[wave][kk] & lmask);
            if (pos < CAP) {
                pairs[kk * CAP + pos] = j;
                npos[i * 27 + s] = kk * CAP + pos;
            } else {
                npos[i * 27 + s] = -1;
            }
        }
        return;
    }

    // ---- conv1 role: Cin=3 -> 128, compacted gather, bf16 out ----
    const int i = (blockIdx.x - nb) * 4 + wave;
    if (i >= n) return;
    const int c2 = lane * 2;

    const int cnt = vcnt[i];
    float f0 = feat[i * 3 + 0];
    float f1 = feat[i * 3 + 1];
    float f2 = feat[i * 3 + 2];

    const float* wc = w1 + 13 * 384 + c2;
    float2 w0 = *(const float2*)(wc);
    float2 wv1 = *(const float2*)(wc + 128);
    float2 w2_ = *(const float2*)(wc + 256);
    float a0 = f0 * w0.x + f1 * wv1.x + f2 * w2_.x;
    float a1 = f0 * w0.y + f1 * wv1.y + f2 * w2_.y;

    for (int s = 0; s < cnt; ++s) {          // wave-uniform trip count
        int e = nbrc[i * 27 + s];
        int k = e >> 20, jj = e & 0xFFFFF;
        float g0 = feat[jj * 3 + 0];
        float g1 = feat[jj * 3 + 1];
        float g2 = feat[jj * 3 + 2];
        const float* wk = w1 + k * 384 + c2;
        float2 u0 = *(const float2*)(wk);
        float2 u1 = *(const float2*)(wk + 128);
        float2 u2 = *(const float2*)(wk + 256);
        a0 += g0 * u0.x + g1 * u1.x + g2 * u2.x;
        a1 += g0 * u0.y + g1 * u1.y + g2 * u2.y;
    }

    unsigned int packed = (unsigned int)f32_to_bf16(a0) |
                          ((unsigned int)f32_to_bf16(a1) << 16);
    *(unsigned int*)(hout + (size_t)i * 128 + c2) = packed;
}

// ---------------- conv2ab: corr GEMM + center GEMM, one dispatch ------------
// conv2b role: bucketed gather-GEMM -> bf16 corr rows (plain stores).
// conv2a role: dense center GEMM -> out (plain stores, NO epilogue gather --
// R10 lesson: dependent gathers in an MFMA epilogue tank VGPR/MLP).
__global__ __launch_bounds__(256, 2) void conv2ab_kernel(
    const unsigned short* __restrict__ h,
    const unsigned short* __restrict__ w2t,
    const int* __restrict__ pairs, const int* __restrict__ cnts,
    unsigned short* __restrict__ corr,
    float* __restrict__ out, int n) {
    const int t = threadIdx.x;
    const int wave = t >> 6, lane = t & 63;
    const int lane16 = lane & 15, quad = lane >> 4;
    const int wm = wave >> 1, wn = wave & 1;

    if (blockIdx.x < 26 * 32) {
        // ---- conv2b role ----
        const int kb = blockIdx.x >> 5;
        const int tile = blockIdx.x & 31;
        const int cnt = min(cnts[kb * CNTS], CAP);
        const int base = tile * 128;
        if (base >= cnt) return;              // uniform early-exit
        const int m = min(128, cnt - base);
        const int k = kb + (kb >= 13);
        const int* pk = pairs + kb * CAP + base;

        short8 a[4][4];
#pragma unroll
        for (int ms = 0; ms < 4; ++ms) {
            int r = wm * 64 + ms * 16 + lane16;
            bool v = (r < m);
            int j = v ? pk[r] : 0;
            const unsigned short* hp = h + (size_t)j * 128 + quad * 8;
#pragma unroll
            for (int ks = 0; ks < 4; ++ks)
                a[ms][ks] = v ? *(const short8*)(hp + ks * 32)
                              : (short8){0, 0, 0, 0, 0, 0, 0, 0};
        }

        short8 b[4][4];
        const unsigned short* wbase = w2t + (size_t)k * 16384 + quad * 8;
#pragma unroll
        for (int ns = 0; ns < 4; ++ns) {
            int c = wn * 64 + ns * 16 + lane16;
            const unsigned short* wp = wbase + c * 128;
#pragma unroll
            for (int ks = 0; ks < 4; ++ks)
                b[ns][ks] = *(const short8*)(wp + ks * 32);
        }

        f32x4 acc[4][4];
#pragma unroll
        for (int p = 0; p < 4; ++p)
#pragma unroll
            for (int q = 0; q < 4; ++q) acc[p][q] = (f32x4){0.f, 0.f, 0.f, 0.f};

#pragma unroll
        for (int ks = 0; ks < 4; ++ks)
#pragma unroll
            for (int ns = 0; ns < 4; ++ns)
#pragma unroll
                for (int ms = 0; ms < 4; ++ms)
                    acc[ms][ns] = __builtin_amdgcn_mfma_f32_16x16x32_bf16(
                        a[ms][ks], b[ns][ks], acc[ms][ns], 0, 0, 0);

#pragma unroll
        for (int ms = 0; ms < 4; ++ms) {
#pragma unroll
            for (int r = 0; r < 4; ++r) {
                int row = wm * 64 + ms * 16 + quad * 4 + r;
                if (row < m) {
                    unsigned short* cr =
                        corr + (size_t)(kb * CAP + base + row) * 128;
#pragma unroll
                    for (int ns = 0; ns < 4; ++ns) {
                        int col = wn * 64 + ns * 16 + lane16;
                        cr[col] = f32_to_bf16(acc[ms][ns][r]);
                    }
                }
            }
        }
        return;
    }

    // ---- conv2a role ----
    const int row0 = (blockIdx.x - 26 * 32) * 128;

    short8 a[4][4];
#pragma unroll
    for (int ms = 0; ms < 4; ++ms) {
        int r = row0 + wm * 64 + ms * 16 + lane16;
        r = min(r, n - 1);                        // clamp: dup rows, never OOB
        const unsigned short* hp = h + (size_t)r * 128 + quad * 8;
#pragma unroll
        for (int ks = 0; ks < 4; ++ks)
            a[ms][ks] = *(const short8*)(hp + ks * 32);
    }

    short8 b[4][4];
    const unsigned short* wbase = w2t + 13 * 16384 + quad * 8;
#pragma unroll
    for (int ns = 0; ns < 4; ++ns) {
        int c = wn * 64 + ns * 16 + lane16;
        const unsigned short* wp = wbase + c * 128;
#pragma unroll
        for (int ks = 0; ks < 4; ++ks)
            b[ns][ks] = *(const short8*)(wp + ks * 32);
    }

    f32x4 acc[4][4];
#pragma unroll
    for (int p = 0; p < 4; ++p)
#pragma unroll
        for (int q = 0; q < 4; ++q) acc[p][q] = (f32x4){0.f, 0.f, 0.f, 0.f};

#pragma unroll
    for (int ks = 0; ks < 4; ++ks)
#pragma unroll
        for (int ns = 0; ns < 4; ++ns)
#pragma unroll
            for (int ms = 0; ms < 4; ++ms)
                acc[ms][ns] = __builtin_amdgcn_mfma_f32_16x16x32_bf16(
                    a[ms][ks], b[ns][ks], acc[ms][ns], 0, 0, 0);

#pragma unroll
    for (int ms = 0; ms < 4; ++ms) {
#pragma unroll
        for (int r = 0; r < 4; ++r) {
            int i = row0 + wm * 64 + ms * 16 + quad * 4 + r;
            if (i < n) {
#pragma unroll
                for (int ns = 0; ns < 4; ++ns) {
                    int col = wn * 64 + ns * 16 + lane16;
                    out[(size_t)i * 128 + col] = acc[ms][ns][r];
                }
            }
        }
    }
}

// ---------------- fixup: wave per row, early-out empty, lanes span 128 cols -
// Dedicated wide kernel: thousands of independent waves hide the corr-gather
// latency that killed the fused epilogue (R10).
__global__ __launch_bounds__(256) void fixup_kernel(
    const unsigned short* __restrict__ corr, const int* __restrict__ vcnt,
    const int* __restrict__ npos, float* __restrict__ out, int n) {
    const int i = blockIdx.x * 4 + (threadIdx.x >> 6);
    const int lane = threadIdx.x & 63;
    if (i >= n) return;
    const int cnt = vcnt[i];
    if (cnt == 0) return;
    const int* np = npos + i * 27;

    float a0 = 0.f, a1 = 0.f;
    for (int s = 0; s < cnt; ++s) {
        int p = np[s];                      // wave-uniform scalar load
        if (p >= 0) {
            unsigned int u =
                *(const unsigned int*)(corr + (size_t)p * 128 + lane * 2);
            a0 += __uint_as_float(u << 16);
            a1 += __uint_as_float(u & 0xFFFF0000u);
        }
    }
    float2* op = (float2*)(out + (size_t)i * 128) + lane;
    float2 cur = *op;
    cur.x += a0;
    cur.y += a1;
    *op = cur;
}

// ---------------- launch ----------------
extern "C" void kernel_launch(void* const* d_in, const int* in_sizes, int n_in,
                              void* d_out, int out_size, void* d_ws,
                              size_t ws_size, hipStream_t stream) {
    const float* feat = (const float*)d_in[0];   // [n][3] f32
    const int* coors = (const int*)d_in[1];      // [n][4] i32
    const float* w1 = (const float*)d_in[2];     // [27][3][128] f32
    const float* w2 = (const float*)d_in[3];     // [27][128][128] f32
    float* out = (float*)d_out;                  // [n][128] f32

    const int n = in_sizes[0] / 3;
    const int nb = (n + 255) / 256;              // voxel blocks

    uint8_t* ws = (uint8_t*)d_ws;
    size_t off = 0;
    int* grid = (int*)(ws + off); off += (size_t)GDHW * 4;            // 32 MB
    unsigned int* bitgrid = (unsigned int*)(ws + off);
    off += (size_t)(GDHW / 8);                                        // 1 MB
    int* vcnt = (int*)(ws + off); off += (size_t)n * 4;               // 0.6 MB
    int* nbrc = (int*)(ws + off); off += (size_t)n * 27 * 4;          // 16.2 MB
    int* npos = (int*)(ws + off); off += (size_t)n * 27 * 4;          // 16.2 MB
    off = (off + 255) & ~(size_t)255;
    unsigned long long* wmask = (unsigned long long*)(ws + off);
    off += (size_t)nb * 4 * 26 * 8;                                   // 0.49 MB
    int* bcnt = (int*)(ws + off); off += (size_t)26 * nb * 4;         // 61 KB
    int* bbase = (int*)(ws + off); off += (size_t)26 * nb * 4;        // 61 KB
    off = (off + 255) & ~(size_t)255;
    unsigned short* hbuf = (unsigned short*)(ws + off);
    off += (size_t)n * 128 * 2;                                       // 38.4 MB
    off = (off + 255) & ~(size_t)255;
    unsigned short* w2t = (unsigned short*)(ws + off);
    off += (size_t)KOFF * 128 * 128 * 2;                              // 0.85 MB
    off = (off + 255) & ~(size_t)255;
    int* pairs = (int*)(ws + off);
    off += (size_t)26 * CAP * 4;                                      // 0.43 MB
    off = (off + 255) & ~(size_t)255;
    int* cnts = (int*)(ws + off); off += 26 * CNTS * 4;               // 3.3 KB
    off = (off + 255) & ~(size_t)255;
    unsigned short* corr = (unsigned short*)(ws + off);
    off += (size_t)26 * CAP * 128 * 2;                                // 27.3 MB

    // only the 1 MB bitmask needs clearing; int grid is read only where bit set
    hipMemsetAsync(bitgrid, 0x00, (size_t)(GDHW / 8), stream);

    const int nbw2 = (NW2 + 255) / 256;
    setup_kernel<<<nb + nbw2, 256, 0, stream>>>(coors, grid, bitgrid, w2, w2t,
                                                n, nb);
    nbr1_kernel<<<nb, 256, 0, stream>>>(coors, grid, bitgrid, vcnt, nbrc,
                                        wmask, bcnt, n, nb);
    scan_kernel<<<26, 256, 0, stream>>>(bcnt, bbase, cnts, nb);
    nbr2_conv1_kernel<<<nb + (n + 3) / 4, 256, 0, stream>>>(
        vcnt, nbrc, wmask, bbase, pairs, npos, feat, w1, hbuf, n, nb);
    conv2ab_kernel<<<26 * 32 + (n + 127) / 128, 256, 0, stream>>>(
        hbuf, w2t, pairs, cnts, corr, out, n);
    fixup_kernel<<<(n + 3) / 4, 256, 0, stream>>>(corr, vcnt, npos, out, n);
}